// Round 4
// baseline (380.316 us; speedup 1.0000x reference)
//
#include <hip/hip_runtime.h>
#include <cstdint>

#define D 1024
#define NB 8   // batch

// ---------------------------------------------------------------------------
// Kernel 1: leaves mean. Only leaves 0..7 (t in [0,2048)) are ever consumed.
// vec[b][leaf][d] = mean_{t=0..255} x[b, leaf*256+t, d]
// grid = b(8) x leaf(8) x tchunk(4) = 256 blocks, 256 thr, float4 per thread.
// ---------------------------------------------------------------------------
__global__ void __launch_bounds__(256) leaves_kernel(const float* __restrict__ x,
                                                     float* __restrict__ vec) {
    int blk = blockIdx.x;
    int tc   = blk & 3;
    int leaf = (blk >> 2) & 7;
    int b    = blk >> 5;
    int d = threadIdx.x * 4;
    const float* base = x + ((size_t)(b * 4096 + leaf * 256 + tc * 64)) * D + d;
    float4 acc = make_float4(0.f, 0.f, 0.f, 0.f);
    #pragma unroll 8
    for (int t = 0; t < 64; ++t) {
        float4 v = *(const float4*)(base + (size_t)t * D);
        acc.x += v.x; acc.y += v.y; acc.z += v.z; acc.w += v.w;
    }
    float* o = vec + (b * 8 + leaf) * D + d;
    const float s = 1.0f / 256.0f;
    atomicAdd(o + 0, acc.x * s);
    atomicAdd(o + 1, acc.y * s);
    atomicAdd(o + 2, acc.z * s);
    atomicAdd(o + 3, acc.w * s);
}

// ---------------------------------------------------------------------------
// Kernel 2 (x4 levels): proj[node_g][b][d] += sum_{k in chunk} A[b,k]*Wp[node_g,k,d]
// A for leaf level: vec duplicated (cat = [vec, vec]); otherwise gated child
// activations: gate = p if (p - bt_child) > 0 else 0, with p = proj_child + bp_child.
// grid = nodes x dsub(2) x kchunks; 256 thr; thread covers 2 d-cols (float2).
// Accumulate with fp32 atomics into zeroed proj buffer (proj stores einsum
// WITHOUT bp; bp added at every consumption site).
// ---------------------------------------------------------------------------
template<int CK, bool IS_LEAF>
__global__ void __launch_bounds__(256) tree_mm(const float* __restrict__ Wp,
                                               const float* __restrict__ bp,
                                               const float* __restrict__ bt,
                                               const float* __restrict__ vec,
                                               float* __restrict__ proj,
                                               int node_start, int kchunks, int child_start) {
    __shared__ float A[CK * 8];
    int blk  = blockIdx.x;
    int kc   = blk % kchunks;
    int dsub = (blk / kchunks) & 1;
    int nloc = blk / (kchunks * 2);
    int node_g = node_start + nloc;
    int k0 = kc * CK;

    for (int idx = threadIdx.x; idx < CK * 8; idx += 256) {
        int kk = idx >> 3, b = idx & 7;
        int k = k0 + kk;
        float a;
        if (IS_LEAF) {
            a = vec[(b * 8 + nloc) * D + (k & 1023)];
        } else {
            int child = child_start + 2 * nloc + (k >> 10);
            int k2 = k & 1023;
            float p = proj[((size_t)child * 8 + b) * D + k2] + bp[child * D + k2];
            a = (p - bt[child * D + k2]) > 0.0f ? p : 0.0f;
        }
        A[idx] = a;
    }
    __syncthreads();

    int d0 = dsub * 512 + threadIdx.x * 2;
    const float* w = Wp + ((size_t)node_g * 2048 + k0) * D + d0;
    float2 acc[8];
    #pragma unroll
    for (int b = 0; b < 8; ++b) acc[b] = make_float2(0.f, 0.f);

    #pragma unroll 4
    for (int kk = 0; kk < CK; ++kk) {
        float2 wv = *(const float2*)(w + (size_t)kk * D);
        const float4* ar = (const float4*)&A[kk * 8];
        float4 a0 = ar[0], a1 = ar[1];
        acc[0].x += a0.x * wv.x; acc[0].y += a0.x * wv.y;
        acc[1].x += a0.y * wv.x; acc[1].y += a0.y * wv.y;
        acc[2].x += a0.z * wv.x; acc[2].y += a0.z * wv.y;
        acc[3].x += a0.w * wv.x; acc[3].y += a0.w * wv.y;
        acc[4].x += a1.x * wv.x; acc[4].y += a1.x * wv.y;
        acc[5].x += a1.y * wv.x; acc[5].y += a1.y * wv.y;
        acc[6].x += a1.z * wv.x; acc[6].y += a1.z * wv.y;
        acc[7].x += a1.w * wv.x; acc[7].y += a1.w * wv.y;
    }

    #pragma unroll
    for (int b = 0; b < 8; ++b) {
        float* o = proj + ((size_t)node_g * 8 + b) * D + d0;
        atomicAdd(o + 0, acc[b].x);
        atomicAdd(o + 1, acc[b].y);
    }
}

// ---------------------------------------------------------------------------
// Kernel 3: mixture[b][d] = sum_n softmax(node_w[:,d])[n] * gated(proj[n][b][d])
// 8192 threads total.
// ---------------------------------------------------------------------------
__global__ void __launch_bounds__(256) mixture_kernel(const float* __restrict__ proj,
                                                      const float* __restrict__ bp,
                                                      const float* __restrict__ bt,
                                                      const float* __restrict__ node_w,
                                                      float* __restrict__ mixture) {
    int idx = blockIdx.x * 256 + threadIdx.x;   // 0..8191
    int b = idx >> 10, d = idx & 1023;
    float wv[15];
    float m = -1e30f;
    #pragma unroll
    for (int n = 0; n < 15; ++n) { wv[n] = node_w[n * D + d]; m = fmaxf(m, wv[n]); }
    float s = 0.f;
    #pragma unroll
    for (int n = 0; n < 15; ++n) { wv[n] = expf(wv[n] - m); s += wv[n]; }
    float inv = 1.0f / s;
    float acc = 0.f;
    #pragma unroll
    for (int n = 0; n < 15; ++n) {
        float p = proj[((size_t)n * 8 + b) * D + d] + bp[n * D + d];
        float g = (p - bt[n * D + d]) > 0.0f ? p : 0.0f;
        acc += wv[n] * inv * g;
    }
    mixture[idx] = acc;
}

// ---------------------------------------------------------------------------
// Kernel 4: out[b,t,:] = LN(x[b,t,:] + mixture[b,:]) * gamma + beta
// one block (256 thr, float4/thread) per row; 32768 blocks.
// ---------------------------------------------------------------------------
__global__ void __launch_bounds__(256) ln_kernel(const float* __restrict__ x,
                                                 const float* __restrict__ mixture,
                                                 const float* __restrict__ gamma,
                                                 const float* __restrict__ beta,
                                                 float* __restrict__ out) {
    int row = blockIdx.x;          // b*4096 + t
    int b = row >> 12;
    size_t base = (size_t)row * D;
    int d = threadIdx.x * 4;

    float4 v  = *(const float4*)(x + base + d);
    float4 mx = *(const float4*)(mixture + b * D + d);
    v.x += mx.x; v.y += mx.y; v.z += mx.z; v.w += mx.w;

    float sum = v.x + v.y + v.z + v.w;
    float sq  = v.x * v.x + v.y * v.y + v.z * v.z + v.w * v.w;

    #pragma unroll
    for (int off = 32; off > 0; off >>= 1) {
        sum += __shfl_down(sum, off);
        sq  += __shfl_down(sq, off);
    }
    __shared__ float s1[4], s2[4];
    int lane = threadIdx.x & 63, wid = threadIdx.x >> 6;
    if (lane == 0) { s1[wid] = sum; s2[wid] = sq; }
    __syncthreads();
    float tot   = s1[0] + s1[1] + s1[2] + s1[3];
    float totsq = s2[0] + s2[1] + s2[2] + s2[3];
    float mu  = tot * (1.0f / D);
    float var = totsq * (1.0f / D) - mu * mu;
    float rstd = rsqrtf(var + 1e-5f);

    float4 g  = *(const float4*)(gamma + d);
    float4 be = *(const float4*)(beta + d);
    float4 o;
    o.x = (v.x - mu) * rstd * g.x + be.x;
    o.y = (v.y - mu) * rstd * g.y + be.y;
    o.z = (v.z - mu) * rstd * g.z + be.z;
    o.w = (v.w - mu) * rstd * g.w + be.w;
    *(float4*)(out + base + d) = o;
}

// ---------------------------------------------------------------------------
// ws layout (floats):
//   vec     @ 0       : 8*8*1024   = 65536
//   proj    @ 65536   : 15*8*1024  = 122880
//   mixture @ 188416  : 8*1024     = 8192
// total 786432 bytes. zero vec+proj (atomic accumulators) every call.
// ---------------------------------------------------------------------------
extern "C" void kernel_launch(void* const* d_in, const int* in_sizes, int n_in,
                              void* d_out, int out_size, void* d_ws, size_t ws_size,
                              hipStream_t stream) {
    const float* x      = (const float*)d_in[0];
    const float* Wp     = (const float*)d_in[1];
    const float* bp     = (const float*)d_in[2];
    const float* bt     = (const float*)d_in[3];
    // d_in[4] = aw : multiplied by 0.0 in the reference — dead.
    const float* node_w = (const float*)d_in[5];
    const float* gamma  = (const float*)d_in[6];
    const float* beta   = (const float*)d_in[7];
    float* out = (float*)d_out;

    float* ws      = (float*)d_ws;
    float* vec     = ws;
    float* proj    = ws + 65536;
    float* mixture = ws + 188416;

    hipMemsetAsync(d_ws, 0, (size_t)(65536 + 122880) * sizeof(float), stream);

    leaves_kernel<<<256, 256, 0, stream>>>(x, vec);

    // level 3: nodes 7..14 (input = duplicated leaves)
    tree_mm<128, true ><<<8 * 2 * 16,  256, 0, stream>>>(Wp, bp, bt, vec, proj, 7, 16,  0);
    // level 2: nodes 3..6 (children 7..14)
    tree_mm< 64, false><<<4 * 2 * 32,  256, 0, stream>>>(Wp, bp, bt, vec, proj, 3, 32,  7);
    // level 1: nodes 1..2 (children 3..6)
    tree_mm< 32, false><<<2 * 2 * 64,  256, 0, stream>>>(Wp, bp, bt, vec, proj, 1, 64,  3);
    // level 0: node 0 (children 1..2)
    tree_mm< 16, false><<<1 * 2 * 128, 256, 0, stream>>>(Wp, bp, bt, vec, proj, 0, 128, 1);

    mixture_kernel<<<32, 256, 0, stream>>>(proj, bp, bt, node_w, mixture);

    ln_kernel<<<32768, 256, 0, stream>>>(x, mixture, gamma, beta, out);
}